// Round 1
// baseline (8596.408 us; speedup 1.0000x reference)
//
#include <hip/hip_runtime.h>

typedef __bf16 bf16;
typedef __bf16 bf16x8 __attribute__((ext_vector_type(8)));
typedef float f32x4 __attribute__((ext_vector_type(4)));

#define T_STEPS 256
#define B_DIM 128
#define D_DIM 1024
#define H_DIM 1024
#define K_DIM 2048  // D + H

// ---------------------------------------------------------------------------
// Init: convert weights (Wf,Wi,Wg,Wo -> packed W4b [4][H][K]), Wout -> bf16,
// x slice t=0 -> bf16, zero h0 and c. Runs every call (ws is re-poisoned).
// ---------------------------------------------------------------------------
__global__ void init_kernel(const float* __restrict__ Wf, const float* __restrict__ Wi,
                            const float* __restrict__ Wg, const float* __restrict__ Wo,
                            const float* __restrict__ Wout, const float* __restrict__ x,
                            bf16* __restrict__ W4b, bf16* __restrict__ Woutb,
                            bf16* __restrict__ xb0, bf16* __restrict__ h0,
                            float* __restrict__ cst) {
    int gid = blockIdx.x * blockDim.x + threadIdx.x;
    int stride = gridDim.x * blockDim.x;
    const int WN = H_DIM * K_DIM;  // 2,097,152 per gate
    for (int i = gid; i < WN; i += stride) {
        W4b[i]          = (bf16)Wf[i];   // gate 0 -> i_t   (naming swap per ref)
        W4b[WN + i]     = (bf16)Wi[i];   // gate 1 -> f_t
        W4b[2*WN + i]   = (bf16)Wg[i];   // gate 2 -> g_t
        W4b[3*WN + i]   = (bf16)Wo[i];   // gate 3 -> o_t
    }
    for (int i = gid; i < 1024 * 1024; i += stride) Woutb[i] = (bf16)Wout[i];
    for (int i = gid; i < B_DIM * H_DIM; i += stride) {
        xb0[i] = (bf16)x[i];
        h0[i]  = (bf16)0.0f;
        cst[i] = 0.0f;
    }
}

// ---------------------------------------------------------------------------
// One LSTM step. Grid = 64 WGs (r-tile of 16 hidden cols x 4 gates = 64 N
// cols each, M = full batch 128). 512 threads = 8 waves; wave = (gate q,
// m-half mh). K-loop BK=64 stages S=[x_t|h] (128x64) and W (64x64) in LDS,
// then 16x16x32 bf16 MFMA. Gate combine fused via LDS z-exchange; also
// converts next step's x slice to bf16.
// ---------------------------------------------------------------------------
__global__ __launch_bounds__(512) void lstm_step_kernel(
    const bf16* __restrict__ W4b,
    const float* __restrict__ bG0, const float* __restrict__ bG1,
    const float* __restrict__ bG2, const float* __restrict__ bG3,
    const bf16* __restrict__ xb_cur, bf16* __restrict__ xb_next,
    const float* __restrict__ x_next_src,
    const bf16* __restrict__ h_in, bf16* __restrict__ h_out,
    float* __restrict__ cst) {
    // 72 = 64 + 8 pad: keeps ds_read_b128 at <=2-way bank aliasing (free)
    __shared__ alignas(16) bf16 Slds[128 * 72];
    __shared__ alignas(16) bf16 Wlds[64 * 72];
    __shared__ float zlds[128 * 4 * 16];  // [b][gate][rc]

    const int tid  = threadIdx.x;
    const int lane = tid & 63;
    const int wave = tid >> 6;   // 0..7
    const int q    = wave & 3;   // gate
    const int mh   = wave >> 1 >> 1;  // wave>>2: m-half 0..1
    const int l16  = lane & 15;
    const int l4   = lane >> 4;  // 0..3
    const int r0   = blockIdx.x * 16;

    f32x4 acc[4];
    #pragma unroll
    for (int i = 0; i < 4; ++i) acc[i] = (f32x4){0.f, 0.f, 0.f, 0.f};

    for (int k0 = 0; k0 < K_DIM; k0 += 64) {
        // stage S tile [128][64]: 1024 chunks of 8 bf16 (16B), 2 per thread
        #pragma unroll
        for (int i = 0; i < 2; ++i) {
            int cidx = tid + i * 512;
            int row  = cidx >> 3;
            int c8   = cidx & 7;
            int kg   = k0 + c8 * 8;
            const bf16* src = (kg < D_DIM) ? (xb_cur + row * D_DIM + kg)
                                           : (h_in + row * H_DIM + (kg - D_DIM));
            *(uint4*)(&Slds[row * 72 + c8 * 8]) = *(const uint4*)src;
        }
        // stage W tile [64 rows = 4 gates x 16 r][64]: 512 chunks, 1 per thread
        {
            int row = tid >> 3;   // 0..63
            int c8  = tid & 7;
            int qq  = row >> 4, rr = row & 15;
            const bf16* src = W4b + (size_t)(qq * H_DIM + r0 + rr) * K_DIM + k0 + c8 * 8;
            *(uint4*)(&Wlds[row * 72 + c8 * 8]) = *(const uint4*)src;
        }
        __syncthreads();
        #pragma unroll
        for (int kk = 0; kk < 64; kk += 32) {
            // B-operand: lane holds W[n = r0+l16 of gate q][k = kk + l4*8 + j]
            bf16x8 bfrag = *(const bf16x8*)(&Wlds[(q * 16 + l16) * 72 + kk + l4 * 8]);
            #pragma unroll
            for (int mt = 0; mt < 4; ++mt) {
                int mrow = mh * 64 + mt * 16 + l16;
                bf16x8 afrag = *(const bf16x8*)(&Slds[mrow * 72 + kk + l4 * 8]);
                acc[mt] = __builtin_amdgcn_mfma_f32_16x16x32_bf16(afrag, bfrag, acc[mt], 0, 0, 0);
            }
        }
        __syncthreads();
    }

    // z -> LDS with bias (C/D layout: row = l4*4 + r, col = l16)
    const float* bias = (q == 0) ? bG0 : (q == 1) ? bG1 : (q == 2) ? bG2 : bG3;
    float bv = bias[r0 + l16];
    #pragma unroll
    for (int mt = 0; mt < 4; ++mt) {
        #pragma unroll
        for (int r = 0; r < 4; ++r) {
            int m = mh * 64 + mt * 16 + l4 * 4 + r;
            zlds[(m * 4 + q) * 16 + l16] = acc[mt][r] + bv;
        }
    }
    __syncthreads();

    // gate combine: each (b, rc) owned by exactly one thread
    #pragma unroll
    for (int i = 0; i < 4; ++i) {
        int idx = tid + i * 512;   // 0..2047 = 128 b x 16 rc
        int b   = idx >> 4;
        int rc  = idx & 15;
        float zi = zlds[(b * 4 + 0) * 16 + rc];
        float zf = zlds[(b * 4 + 1) * 16 + rc];
        float zg = zlds[(b * 4 + 2) * 16 + rc];
        float zo = zlds[(b * 4 + 3) * 16 + rc];
        float ig = 1.0f / (1.0f + __expf(-zi));
        float fg = 1.0f / (1.0f + __expf(-zf));
        float gg = tanhf(zg);
        float og = 1.0f / (1.0f + __expf(-zo));
        int ci = b * H_DIM + r0 + rc;
        float cv = fg * cst[ci] + ig * gg;
        cst[ci] = cv;
        h_out[ci] = (bf16)(og * tanhf(cv));
    }

    // convert next step's x slice to bf16 (64 WG x 512 thr x 4 = 131072)
    if (x_next_src != nullptr) {
        int g0 = (blockIdx.x * 512 + tid) * 4;
        float4 v = *(const float4*)(x_next_src + g0);
        xb_next[g0 + 0] = (bf16)v.x;
        xb_next[g0 + 1] = (bf16)v.y;
        xb_next[g0 + 2] = (bf16)v.z;
        xb_next[g0 + 3] = (bf16)v.w;
    }
}

// ---------------------------------------------------------------------------
// logits = h_T @ Wout^T + bout. M=128, N=1024, K=1024. Grid 64 (n-tile 16),
// 512 thr = 8 waves, wave w owns m-tile rows [16w, 16w+16).
// ---------------------------------------------------------------------------
__global__ __launch_bounds__(512) void final_gemm_kernel(
    const bf16* __restrict__ hfin, const bf16* __restrict__ Woutb,
    const float* __restrict__ bout, float* __restrict__ logits) {
    __shared__ alignas(16) bf16 Slds[128 * 72];
    const int tid  = threadIdx.x;
    const int lane = tid & 63;
    const int wave = tid >> 6;
    const int l16  = lane & 15;
    const int l4   = lane >> 4;
    const int n0   = blockIdx.x * 16;
    f32x4 acc = (f32x4){0.f, 0.f, 0.f, 0.f};
    for (int k0 = 0; k0 < H_DIM; k0 += 64) {
        #pragma unroll
        for (int i = 0; i < 2; ++i) {
            int cidx = tid + i * 512;
            int row = cidx >> 3, c8 = cidx & 7;
            *(uint4*)(&Slds[row * 72 + c8 * 8]) =
                *(const uint4*)(hfin + row * H_DIM + k0 + c8 * 8);
        }
        __syncthreads();
        #pragma unroll
        for (int kk = 0; kk < 64; kk += 32) {
            bf16x8 bfrag = *(const bf16x8*)(Woutb + (size_t)(n0 + l16) * H_DIM + k0 + kk + l4 * 8);
            bf16x8 afrag = *(const bf16x8*)(&Slds[(wave * 16 + l16) * 72 + kk + l4 * 8]);
            acc = __builtin_amdgcn_mfma_f32_16x16x32_bf16(afrag, bfrag, acc, 0, 0, 0);
        }
        __syncthreads();
    }
    float bv = bout[n0 + l16];
    #pragma unroll
    for (int r = 0; r < 4; ++r) {
        int m = wave * 16 + l4 * 4 + r;
        logits[m * 1024 + n0 + l16] = acc[r] + bv;
    }
}

// ---------------------------------------------------------------------------
// Row-wise log_softmax over 1024 logits. Grid 128 (one WG per batch row).
// ---------------------------------------------------------------------------
__global__ __launch_bounds__(256) void logsoftmax_kernel(
    const float* __restrict__ logits, float* __restrict__ out) {
    int b = blockIdx.x, tid = threadIdx.x;
    int lane = tid & 63, wv = tid >> 6;
    __shared__ float red[4];
    float v[4];
    float mx = -1e30f;
    #pragma unroll
    for (int i = 0; i < 4; ++i) {
        v[i] = logits[b * 1024 + i * 256 + tid];
        mx = fmaxf(mx, v[i]);
    }
    #pragma unroll
    for (int off = 1; off < 64; off <<= 1) mx = fmaxf(mx, __shfl_xor(mx, off));
    if (lane == 0) red[wv] = mx;
    __syncthreads();
    mx = fmaxf(fmaxf(red[0], red[1]), fmaxf(red[2], red[3]));
    float s = 0.f;
    #pragma unroll
    for (int i = 0; i < 4; ++i) s += __expf(v[i] - mx);
    #pragma unroll
    for (int off = 1; off < 64; off <<= 1) s += __shfl_xor(s, off);
    __syncthreads();
    if (lane == 0) red[wv] = s;
    __syncthreads();
    s = red[0] + red[1] + red[2] + red[3];
    float lse = mx + __logf(s);
    #pragma unroll
    for (int i = 0; i < 4; ++i) out[b * 1024 + i * 256 + tid] = v[i] - lse;
}

extern "C" void kernel_launch(void* const* d_in, const int* in_sizes, int n_in,
                              void* d_out, int out_size, void* d_ws, size_t ws_size,
                              hipStream_t stream) {
    const float* x    = (const float*)d_in[0];
    const float* Wf   = (const float*)d_in[1];
    const float* bfv  = (const float*)d_in[2];
    const float* Wi   = (const float*)d_in[3];
    const float* biv  = (const float*)d_in[4];
    const float* Wg   = (const float*)d_in[5];
    const float* bgv  = (const float*)d_in[6];
    const float* Wo   = (const float*)d_in[7];
    const float* bov  = (const float*)d_in[8];
    const float* Wout = (const float*)d_in[9];
    const float* bout = (const float*)d_in[10];
    float* out = (float*)d_out;

    // ws layout (~21 MB total)
    char* p = (char*)d_ws;
    bf16* W4b    = (bf16*)p;  p += (size_t)4 * 1024 * 2048 * 2;   // 16 MB
    bf16* Woutb  = (bf16*)p;  p += (size_t)1024 * 1024 * 2;       //  2 MB
    bf16* hb     = (bf16*)p;  p += (size_t)2 * 131072 * 2;        // h double-buffer
    bf16* xb     = (bf16*)p;  p += (size_t)2 * 131072 * 2;        // x-slice double-buffer
    float* cst   = (float*)p; p += (size_t)131072 * 4;            // cell state
    float* logits= (float*)p; p += (size_t)131072 * 4;
    if (ws_size < (size_t)(p - (char*)d_ws)) return;  // ws too small: fail loudly

    init_kernel<<<1024, 256, 0, stream>>>(Wf, Wi, Wg, Wo, Wout, x, W4b, Woutb,
                                          xb, hb, cst);
    for (int t = 0; t < T_STEPS; ++t) {
        const bf16* xcur = xb + (t & 1) * 131072;
        bf16* xnext      = xb + ((t + 1) & 1) * 131072;
        const float* xsrc = (t + 1 < T_STEPS) ? (x + (size_t)(t + 1) * 131072) : nullptr;
        const bf16* hin  = hb + (t & 1) * 131072;
        bf16* hout       = hb + ((t + 1) & 1) * 131072;
        lstm_step_kernel<<<64, 512, 0, stream>>>(W4b, bfv, biv, bgv, bov,
                                                 xcur, xnext, xsrc, hin, hout, cst);
    }
    // after step 255, h lives in buffer (256 & 1) == 0
    final_gemm_kernel<<<64, 512, 0, stream>>>(hb, Woutb, bout, logits);
    logsoftmax_kernel<<<128, 256, 0, stream>>>(logits, out);
}